// Round 4
// baseline (142.249 us; speedup 1.0000x reference)
//
#include <hip/hip_runtime.h>
#include <stdint.h>

#define TOK 256
#define IN_F 4096
#define OUT_F 4096
#define N_OUT 32
#define BN 16

typedef int v4i __attribute__((ext_vector_type(4)));

// asm-forced global load: compiler cannot sink or collapse the ring
#define ALD(D, P, OFF) \
    asm volatile("global_load_dwordx4 %0, %1, off offset:" OFF \
                 : "=v"(D) : "v"(P) : "memory")
#define WAITV(N) asm volatile("s_waitcnt vmcnt(" N ")" ::: "memory")

// ---------------- Kernel 1: rowwise masked quantization ----------------
__global__ __launch_bounds__(256) void oal_quant(
    const float* __restrict__ x, const int* __restrict__ oidx,
    int8_t* __restrict__ xq, float* __restrict__ xs, float* __restrict__ xo)
{
    const int row = blockIdx.x;
    const int tid = threadIdx.x;
    __shared__ unsigned char flags[IN_F];
    __shared__ float wmax[4];
    __shared__ float s_scale;

    const float* xr = x + (size_t)row * IN_F;
    float4 v[4];
    const float4* xp = reinterpret_cast<const float4*>(xr + tid * 16);
    #pragma unroll
    for (int i = 0; i < 4; ++i) v[i] = xp[i];

    *reinterpret_cast<uint4*>(&flags[tid * 16]) = make_uint4(0u, 0u, 0u, 0u);
    __syncthreads();
    if (tid < N_OUT) flags[oidx[tid]] = 1;
    __syncthreads();

    uint4 f = *reinterpret_cast<const uint4*>(&flags[tid * 16]);
    unsigned int fw[4] = { f.x, f.y, f.z, f.w };
    float vals[16];
    #pragma unroll
    for (int i = 0; i < 4; ++i) {
        vals[i*4+0] = ((fw[i]      ) & 255u) ? 0.0f : v[i].x;
        vals[i*4+1] = ((fw[i] >>  8) & 255u) ? 0.0f : v[i].y;
        vals[i*4+2] = ((fw[i] >> 16) & 255u) ? 0.0f : v[i].z;
        vals[i*4+3] = ((fw[i] >> 24) & 255u) ? 0.0f : v[i].w;
    }

    float m = 0.0f;
    #pragma unroll
    for (int i = 0; i < 16; ++i) m = fmaxf(m, fabsf(vals[i]));
    #pragma unroll
    for (int off = 32; off > 0; off >>= 1) m = fmaxf(m, __shfl_xor(m, off, 64));
    const int lane = tid & 63, wid = tid >> 6;
    if (lane == 0) wmax[wid] = m;
    __syncthreads();
    if (tid == 0) {
        float s = fmaxf(fmaxf(wmax[0], wmax[1]), fmaxf(wmax[2], wmax[3]));
        s_scale = s;
        xs[row] = s;
    }
    __syncthreads();
    const float safe = fmaxf(s_scale, 1e-8f);

    int q[16];
    #pragma unroll
    for (int i = 0; i < 16; ++i) {
        float t = vals[i] / safe * 127.0f;        // exact reference order
        t = fminf(127.0f, fmaxf(-127.0f, rintf(t)));
        q[i] = (int)t;
    }
    uint4 packed;
    unsigned int* pw = &packed.x;
    #pragma unroll
    for (int i = 0; i < 4; ++i)
        pw[i] = (unsigned)(q[i*4] & 255) | ((unsigned)(q[i*4+1] & 255) << 8)
              | ((unsigned)(q[i*4+2] & 255) << 16) | ((unsigned)(q[i*4+3] & 255) << 24);
    *reinterpret_cast<uint4*>(xq + (size_t)row * IN_F + tid * 16) = packed;

    if (tid < N_OUT) xo[row * N_OUT + tid] = xr[oidx[tid]];
}

// ---------------- Kernel 2: int8 MFMA GEMM ----------------
// 256 blocks x 512 threads (1/CU). Phase 1: bulk-stage the block's whole
// 16-row weight panel (256 KB int32) and pack to int8 into 64 KB LDS in
// MFMA-fragment order [ks][row][64B] (conflict-free reads). One barrier.
// Phase 2: 64 ksteps, NO barriers: per-wave A-register ring 8 deep via
// inline-asm global_load_dwordx4 + counted vmcnt(14); 1 ds_read_b128 + 2 MFMA.
__global__ __launch_bounds__(512, 2) void oal_gemm(
    const int8_t* __restrict__ xq, const int* __restrict__ wgt,
    const float* __restrict__ xs, const float* __restrict__ wscale,
    const float* __restrict__ ow, const float* __restrict__ bias,
    const float* __restrict__ xo, float* __restrict__ out)
{
    __shared__ __align__(16) int8_t Bs[64 * 1024];

    const int bn = blockIdx.x;
    const int tid = threadIdx.x;
    const int lane = tid & 63;
    const int wv = tid >> 6;
    const int kof = lane >> 4;

    // ---- Phase 1: stage + pack B ----
    {
        const int r = tid >> 5;            // 0..15  (weight row / output col)
        const int ii = tid & 31;           // 0..31
        const int* gsrc = wgt + (size_t)(bn * BN + r) * IN_F + ii * 4;
        const int lbase = (ii >> 4) * 1024 + r * 64 + (ii & 15) * 4;

        auto packw = [](int4 a) -> unsigned {
            return (unsigned)((a.x & 255) | ((a.y & 255) << 8)
                            | ((a.z & 255) << 16) | ((a.w & 255) << 24));
        };
        int4 sA[8], sB[8];
        #pragma unroll
        for (int j = 0; j < 8; ++j) sA[j] = *reinterpret_cast<const int4*>(gsrc + j * 128);
        #pragma unroll
        for (int j = 0; j < 8; ++j) sB[j] = *reinterpret_cast<const int4*>(gsrc + (8 + j) * 128);
        #pragma unroll
        for (int j = 0; j < 8; ++j) *reinterpret_cast<unsigned*>(&Bs[lbase + j * 2048]) = packw(sA[j]);
        #pragma unroll
        for (int j = 0; j < 8; ++j) sA[j] = *reinterpret_cast<const int4*>(gsrc + (16 + j) * 128);
        #pragma unroll
        for (int j = 0; j < 8; ++j) *reinterpret_cast<unsigned*>(&Bs[lbase + (8 + j) * 2048]) = packw(sB[j]);
        #pragma unroll
        for (int j = 0; j < 8; ++j) sB[j] = *reinterpret_cast<const int4*>(gsrc + (24 + j) * 128);
        #pragma unroll
        for (int j = 0; j < 8; ++j) *reinterpret_cast<unsigned*>(&Bs[lbase + (16 + j) * 2048]) = packw(sA[j]);
        #pragma unroll
        for (int j = 0; j < 8; ++j) *reinterpret_cast<unsigned*>(&Bs[lbase + (24 + j) * 2048]) = packw(sB[j]);
    }
    __syncthreads();

    // ---- Phase 2: compute ----
    const int r0 = wv * 32 + (lane & 15);
    const int8_t* a0p = xq + (size_t)r0 * IN_F + kof * 16;
    const int8_t* a1p = a0p + 16 * IN_F;
    const int8_t* bptr = &Bs[(lane & 15) * 64 + kof * 16];

    v4i ar0[8], ar1[8];
    v4i acc0 = {0,0,0,0}, acc1 = {0,0,0,0};

    // prime ring: ksteps 0..7 (issue order = pair order for vmcnt counting)
    ALD(ar0[0], a0p, "0");   ALD(ar1[0], a1p, "0");
    ALD(ar0[1], a0p, "64");  ALD(ar1[1], a1p, "64");
    ALD(ar0[2], a0p, "128"); ALD(ar1[2], a1p, "128");
    ALD(ar0[3], a0p, "192"); ALD(ar1[3], a1p, "192");
    ALD(ar0[4], a0p, "256"); ALD(ar1[4], a1p, "256");
    ALD(ar0[5], a0p, "320"); ALD(ar1[5], a1p, "320");
    ALD(ar0[6], a0p, "384"); ALD(ar1[6], a1p, "384");
    ALD(ar0[7], a0p, "448"); ALD(ar1[7], a1p, "448");

#define KS(SLOT, KOFF, ROFF) { \
    v4i bv_ = *reinterpret_cast<const v4i*>(bptr + (KOFF) * 1024); \
    WAITV("14"); \
    __builtin_amdgcn_sched_barrier(0); \
    acc0 = __builtin_amdgcn_mfma_i32_16x16x64_i8(ar0[SLOT], bv_, acc0, 0, 0, 0); \
    acc1 = __builtin_amdgcn_mfma_i32_16x16x64_i8(ar1[SLOT], bv_, acc1, 0, 0, 0); \
    ALD(ar0[SLOT], a0p, ROFF); \
    ALD(ar1[SLOT], a1p, ROFF); \
}
#define KT(SLOT, KOFF, VN) { \
    v4i bv_ = *reinterpret_cast<const v4i*>(bptr + (KOFF) * 1024); \
    WAITV(VN); \
    __builtin_amdgcn_sched_barrier(0); \
    acc0 = __builtin_amdgcn_mfma_i32_16x16x64_i8(ar0[SLOT], bv_, acc0, 0, 0, 0); \
    acc1 = __builtin_amdgcn_mfma_i32_16x16x64_i8(ar1[SLOT], bv_, acc1, 0, 0, 0); \
}

    for (int blk = 0; blk < 7; ++blk) {
        KS(0, 0, "512"); KS(1, 1, "576"); KS(2, 2, "640"); KS(3, 3, "704");
        KS(4, 4, "768"); KS(5, 5, "832"); KS(6, 6, "896"); KS(7, 7, "960");
        a0p += 512; a1p += 512; bptr += 8192;
    }
    // tail: ksteps 56..63, ring drains
    KT(0, 0, "14"); KT(1, 1, "12"); KT(2, 2, "10"); KT(3, 3, "8");
    KT(4, 4, "6");  KT(5, 5, "4");  KT(6, 6, "2");  KT(7, 7, "0");
#undef KS
#undef KT

    // ---------------- epilogue ----------------
    const int ocol = bn * BN + (lane & 15);
    const float wsc = wscale[ocol] * (1.0f / 16129.0f);  // /127^2
    const float bo  = bias[ocol];
    float4 owr[8];
    const float4* owp = reinterpret_cast<const float4*>(ow + (size_t)ocol * N_OUT);
    #pragma unroll
    for (int i = 0; i < 8; ++i) owr[i] = owp[i];

    const int rbase = kof * 4;
    const int mrow = wv * 32;
    #pragma unroll
    for (int mt = 0; mt < 2; ++mt) {
        v4i a = mt ? acc1 : acc0;
        #pragma unroll
        for (int r = 0; r < 4; ++r) {
            const int t = mrow + mt * 16 + rbase + r;
            const float4* xr4 = reinterpret_cast<const float4*>(xo + (size_t)t * N_OUT);
            float dot = 0.0f;
            #pragma unroll
            for (int j = 0; j < 8; ++j) {
                float4 o4 = owr[j];
                float4 x4 = xr4[j];
                dot += x4.x*o4.x + x4.y*o4.y + x4.z*o4.z + x4.w*o4.w;
            }
            out[(size_t)t * OUT_F + ocol] = (float)a[r] * (xs[t] * wsc) + bo + dot;
        }
    }
}

extern "C" void kernel_launch(void* const* d_in, const int* in_sizes, int n_in,
                              void* d_out, int out_size, void* d_ws, size_t ws_size,
                              hipStream_t stream) {
    const float* x      = (const float*)d_in[0];
    const int*   w      = (const int*)  d_in[1];
    const float* wscale = (const float*)d_in[2];
    const int*   oidx   = (const int*)  d_in[3];
    const float* ow     = (const float*)d_in[4];
    const float* bias   = (const float*)d_in[5];
    float* out = (float*)d_out;

    int8_t* xq = (int8_t*)d_ws;
    float*  xs = (float*)((char*)d_ws + (size_t)TOK * IN_F);
    float*  xo = (float*)((char*)d_ws + (size_t)TOK * IN_F + 1024);

    oal_quant<<<TOK, 256, 0, stream>>>(x, oidx, xq, xs, xo);
    oal_gemm<<<OUT_F / BN, 512, 0, stream>>>(xq, w, xs, wscale, ow, bias, xo, out);
}

// Round 7
// 122.785 us; speedup vs baseline: 1.1585x; 1.1585x over previous
//
#include <hip/hip_runtime.h>
#include <stdint.h>

#define TOK 256
#define IN_F 4096
#define OUT_F 4096
#define N_OUT 32

typedef int v4i  __attribute__((ext_vector_type(4)));
typedef int v16i __attribute__((ext_vector_type(16)));

__device__ __forceinline__ void gll16(const void* g, void* l) {
    __builtin_amdgcn_global_load_lds((const __attribute__((address_space(1))) void*)g,
                                     (__attribute__((address_space(3))) void*)l, 16, 0, 0);
}

// ---------------- Kernel 1: rowwise masked quantization ----------------
// XQT fragment-order layout (1 MB): for ks32 (32-k step, 0..127), rowgrp
// (32 rows, 0..7): a 1024B block; 16B slot at lane_pos = khalf*32 + (row&31)
// holds row's k bytes [ks32*32 + khalf*16, +16). MFMA A-reads and the GEMM's
// global_load_lds staging are both contiguous by construction.
__global__ __launch_bounds__(256) void oal_quant(
    const float* __restrict__ x, const int* __restrict__ oidx,
    int8_t* __restrict__ xqt, float* __restrict__ xs, float* __restrict__ xo)
{
    const int row = blockIdx.x;
    const int tid = threadIdx.x;
    __shared__ unsigned char flags[IN_F];
    __shared__ float wmax[4];
    __shared__ float s_scale;

    const float* xr = x + (size_t)row * IN_F;
    float4 v[4];
    const float4* xp = reinterpret_cast<const float4*>(xr + tid * 16);
    #pragma unroll
    for (int i = 0; i < 4; ++i) v[i] = xp[i];

    *reinterpret_cast<uint4*>(&flags[tid * 16]) = make_uint4(0u, 0u, 0u, 0u);
    __syncthreads();
    if (tid < N_OUT) flags[oidx[tid]] = 1;
    __syncthreads();

    uint4 f = *reinterpret_cast<const uint4*>(&flags[tid * 16]);
    unsigned int fw[4] = { f.x, f.y, f.z, f.w };
    float vals[16];
    #pragma unroll
    for (int i = 0; i < 4; ++i) {
        vals[i*4+0] = ((fw[i]      ) & 255u) ? 0.0f : v[i].x;
        vals[i*4+1] = ((fw[i] >>  8) & 255u) ? 0.0f : v[i].y;
        vals[i*4+2] = ((fw[i] >> 16) & 255u) ? 0.0f : v[i].z;
        vals[i*4+3] = ((fw[i] >> 24) & 255u) ? 0.0f : v[i].w;
    }

    float m = 0.0f;
    #pragma unroll
    for (int i = 0; i < 16; ++i) m = fmaxf(m, fabsf(vals[i]));
    #pragma unroll
    for (int off = 32; off > 0; off >>= 1) m = fmaxf(m, __shfl_xor(m, off, 64));
    const int lane = tid & 63, wid = tid >> 6;
    if (lane == 0) wmax[wid] = m;
    __syncthreads();
    if (tid == 0) {
        float s = fmaxf(fmaxf(wmax[0], wmax[1]), fmaxf(wmax[2], wmax[3]));
        s_scale = s;
        xs[row] = s;
    }
    __syncthreads();
    const float safe = fmaxf(s_scale, 1e-8f);

    int q[16];
    #pragma unroll
    for (int i = 0; i < 16; ++i) {
        float t = vals[i] / safe * 127.0f;        // exact reference order
        t = fminf(127.0f, fmaxf(-127.0f, rintf(t)));
        q[i] = (int)t;
    }
    uint4 packed;
    unsigned int* pw = &packed.x;
    #pragma unroll
    for (int i = 0; i < 4; ++i)
        pw[i] = (unsigned)(q[i*4] & 255) | ((unsigned)(q[i*4+1] & 255) << 8)
              | ((unsigned)(q[i*4+2] & 255) << 16) | ((unsigned)(q[i*4+3] & 255) << 24);

    // fragment-order store: thread tid holds k [tid*16, +16) of this row
    const int ks32  = tid >> 1;          // 0..127
    const int khalf = tid & 1;
    const int rowgrp = row >> 5;
    *reinterpret_cast<uint4*>(xqt + (size_t)ks32 * 8192 + rowgrp * 1024
                              + (khalf * 32 + (row & 31)) * 16) = packed;

    if (tid < N_OUT) xo[row * N_OUT + tid] = xr[oidx[tid]];
}

// ---------------- Kernel 2: int8 MFMA GEMM, split-K ----------------
// grid 256 = 32 n-tiles (BN=128) x 8 k-slices (512 k). 512 threads, 8 waves
// = 4 row-groups (64 rows) x 2 col-groups (64 cols), 32x32x32 i8 MFMA.
// B: one-col-per-instruction loads (contiguous 1KB/instr), packed int8 into
// 64KB LDS, slot XOR (col^ks32&7) -> 2-way write banks, conflict-free reads.
// A: fragment-order xqt staged via global_load_lds, 32KB chunks, dbuf.
template<int MODE>
__global__ __launch_bounds__(512, 1) void oal_gemm(
    const int8_t* __restrict__ xqt, const int* __restrict__ wgt,
    int* __restrict__ pout)
{
    __shared__ __align__(16) int8_t sm[131072];
    int8_t* As = sm;           // 2 bufs x 32 KB
    int8_t* Bs = sm + 65536;   // 16 ks32 x 4 colgrp x 1024 B

    const int bn = blockIdx.x;
    const int ntile = bn & 31, kslice = bn >> 5;
    const int n0 = ntile * 128;
    const int tid = threadIdx.x, lane = tid & 63, wv = tid >> 6;
    const int mg = wv & 3, ng = wv >> 2;
    const int l31 = lane & 31, lh = lane >> 5;

    auto issueA = [&](int h) {   // chunk h = 4 ks32 = 32 KB, linear copy
        const int8_t* s = xqt + ((size_t)(kslice * 16 + h * 4) << 13) + tid * 16;
        int8_t* d = As + ((h & 1) << 15) + tid * 16;
        gll16(s, d);
        gll16(s + 8192, d + 8192);
        gll16(s + 16384, d + 16384);
        gll16(s + 24576, d + 24576);
    };
    issueA(0);

    // ---- B stage ----
    {
        const int cbase = wv * 16;
        #pragma unroll
        for (int g = 0; g < 4; ++g) {
            int4 t[8];
            #pragma unroll
            for (int j = 0; j < 8; ++j) {
                const int q = g * 8 + j;
                const int c = cbase + (q & 15);
                const int ih = q >> 4;
                t[j] = *reinterpret_cast<const int4*>(
                    wgt + (size_t)(n0 + c) * IN_F + kslice * 512 + ih * 256 + lane * 4);
            }
            #pragma unroll
            for (int j = 0; j < 8; ++j) {
                const int q = g * 8 + j;
                const int c = cbase + (q & 15);
                const int ih = q >> 4;
                unsigned pk = (unsigned)((t[j].x & 255) | ((t[j].y & 255) << 8)
                             | ((t[j].z & 255) << 16) | ((t[j].w & 255) << 24));
                const int ks32l = ih * 8 + (lane >> 3);
                const int addr = ks32l * 4096 + (c >> 5) * 1024
                               + (((lane >> 2) & 1) * 32 + ((c & 31) ^ (lane >> 3))) * 16
                               + (lane & 3) * 4;
                *reinterpret_cast<unsigned*>(Bs + addr) = pk;
            }
        }
    }
    __syncthreads();    // chunk0 A arrived, B packed

    // ---- compute: 16 ks32 steps ----
    v16i acc00 = {}, acc01 = {}, acc10 = {}, acc11 = {};
    const int aoff = (2 * mg) * 1024 + lane * 16;
    #pragma unroll
    for (int h = 0; h < 4; ++h) {
        if (h < 3) issueA(h + 1);
        const int8_t* At = As + ((h & 1) << 15);
        #pragma unroll
        for (int loc = 0; loc < 4; ++loc) {
            const int ks32g = h * 4 + loc;
            const int s7 = ks32g & 7;
            const int8_t* Ap = At + loc * 8192 + aoff;
            const int8_t* Bp = Bs + ks32g * 4096 + (lh * 32 + (l31 ^ s7)) * 16;
            v4i a0 = *reinterpret_cast<const v4i*>(Ap);
            v4i a1 = *reinterpret_cast<const v4i*>(Ap + 1024);
            v4i b0 = *reinterpret_cast<const v4i*>(Bp + (2 * ng) * 1024);
            v4i b1 = *reinterpret_cast<const v4i*>(Bp + (2 * ng + 1) * 1024);
            acc00 = __builtin_amdgcn_mfma_i32_32x32x32_i8(a0, b0, acc00, 0, 0, 0);
            acc01 = __builtin_amdgcn_mfma_i32_32x32x32_i8(a0, b1, acc01, 0, 0, 0);
            acc10 = __builtin_amdgcn_mfma_i32_32x32x32_i8(a1, b0, acc10, 0, 0, 0);
            acc11 = __builtin_amdgcn_mfma_i32_32x32x32_i8(a1, b1, acc11, 0, 0, 0);
        }
        if (h < 3) __syncthreads();
    }

    // ---- write int32 partials ----
    const int colb = n0 + ng * 64 + l31;
    const int rowb = mg * 64 + 4 * lh;
#define OUTW(ACC, MF, NF) { _Pragma("unroll") \
    for (int r = 0; r < 16; ++r) { \
        const int rr = rowb + (MF)*32 + (r & 3) + ((r >> 2) << 3); \
        const size_t off = (size_t)rr * OUT_F + colb + (NF)*32; \
        if (MODE == 0) pout[(size_t)kslice * ((size_t)TOK * OUT_F) + off] = ACC[r]; \
        else atomicAdd(pout + off, ACC[r]); \
    } }
    OUTW(acc00,0,0) OUTW(acc01,0,1) OUTW(acc10,1,0) OUTW(acc11,1,1)
#undef OUTW
}

// ---------------- Kernel 3: reduce partials + fused epilogue ----------------
template<int MODE>
__global__ __launch_bounds__(256) void oal_epi(
    float* __restrict__ outp, const int* __restrict__ part,
    const float* __restrict__ xs, const float* __restrict__ wscale,
    const float* __restrict__ ow, const float* __restrict__ bias,
    const float* __restrict__ xo)
{
    const int rb = blockIdx.x >> 3;      // rows rb*8 .. +8
    const int cb = blockIdx.x & 7;       // cols cb*512 .. +512
    const int tid = threadIdx.x;
    const int c0 = cb * 512 + tid * 2;

    __shared__ float sxo[8][32];
    __shared__ float sxs[8];
    if (tid < 64) {
        const int rr = tid >> 3, jj = tid & 7;
        *reinterpret_cast<float4*>(&sxo[rr][jj * 4]) =
            *reinterpret_cast<const float4*>(xo + (size_t)(rb * 8 + rr) * N_OUT + jj * 4);
    }
    if (tid < 8) sxs[tid] = xs[rb * 8 + tid];
    __syncthreads();

    float o0[32], o1[32];
    #pragma unroll
    for (int j = 0; j < 8; ++j) {
        float4 f0 = reinterpret_cast<const float4*>(ow + (size_t)c0 * N_OUT)[j];
        float4 f1 = reinterpret_cast<const float4*>(ow + (size_t)(c0 + 1) * N_OUT)[j];
        o0[j*4+0]=f0.x; o0[j*4+1]=f0.y; o0[j*4+2]=f0.z; o0[j*4+3]=f0.w;
        o1[j*4+0]=f1.x; o1[j*4+1]=f1.y; o1[j*4+2]=f1.z; o1[j*4+3]=f1.w;
    }
    const float wsc0 = wscale[c0]     * (1.0f / 16129.0f);
    const float wsc1 = wscale[c0 + 1] * (1.0f / 16129.0f);
    const float bo0 = bias[c0], bo1 = bias[c0 + 1];

    #pragma unroll
    for (int r = 0; r < 8; ++r) {
        const int row = rb * 8 + r;
        const size_t off = (size_t)row * OUT_F + c0;
        int px = 0, py = 0;
        if (MODE == 0) {
            #pragma unroll
            for (int s2 = 0; s2 < 8; ++s2) {
                int2 t = *reinterpret_cast<const int2*>(
                    part + (size_t)s2 * ((size_t)TOK * OUT_F) + off);
                px += t.x; py += t.y;
            }
        } else {
            int2 t = *reinterpret_cast<const int2*>(reinterpret_cast<const int*>(outp) + off);
            px = t.x; py = t.y;
        }
        float d0 = 0.f, d1 = 0.f;
        #pragma unroll
        for (int k = 0; k < 32; ++k) {
            const float xv = sxo[r][k];
            d0 += xv * o0[k]; d1 += xv * o1[k];
        }
        const float s = sxs[r];
        float2 res;
        res.x = (float)px * (s * wsc0) + d0 + bo0;
        res.y = (float)py * (s * wsc1) + d1 + bo1;
        *reinterpret_cast<float2*>(outp + off) = res;
    }
}

extern "C" void kernel_launch(void* const* d_in, const int* in_sizes, int n_in,
                              void* d_out, int out_size, void* d_ws, size_t ws_size,
                              hipStream_t stream) {
    const float* x      = (const float*)d_in[0];
    const int*   w      = (const int*)  d_in[1];
    const float* wscale = (const float*)d_in[2];
    const int*   oidx   = (const int*)  d_in[3];
    const float* ow     = (const float*)d_in[4];
    const float* bias   = (const float*)d_in[5];
    float* out = (float*)d_out;

    int8_t* xqt = (int8_t*)d_ws;
    float*  xs  = (float*)((char*)d_ws + (1 << 20));
    float*  xo  = (float*)((char*)d_ws + (1 << 20) + 1024);
    int*    P2  = (int*)  ((char*)d_ws + (1 << 20) + 1024 + 32768);
    const size_t need = (size_t)(1 << 20) + 1024 + 32768 + (size_t)8 * TOK * OUT_F * 4;

    oal_quant<<<TOK, 256, 0, stream>>>(x, oidx, xqt, xs, xo);
    if (ws_size >= need) {
        oal_gemm<0><<<256, 512, 0, stream>>>(xqt, w, P2);
        oal_epi<0><<<256, 256, 0, stream>>>(out, P2, xs, wscale, ow, bias, xo);
    } else {
        hipMemsetAsync(d_out, 0, (size_t)TOK * OUT_F * 4, stream);
        oal_gemm<1><<<256, 512, 0, stream>>>(xqt, w, (int*)d_out);
        oal_epi<1><<<256, 256, 0, stream>>>(out, (const int*)d_out, xs, wscale, ow, bias, xo);
    }
}